// Round 1
// baseline (1104.297 us; speedup 1.0000x reference)
//
#include <hip/hip_runtime.h>

// ---------------- problem constants ----------------
#define NROWS   131072
#define KDIM    1024
#define NLVL    4
#define SLOT_CAP 131584            // 131072 + 4*128 padding

// ---------------- ws layout (bytes) ----------------
#define OFF_IDX  1024ull
#define OFF_PART (OFF_IDX + (size_t)SLOT_CAP * 4)                 // 527360
#define OFF_WT1  (OFF_PART + (size_t)SLOT_CAP * 64)               // 8948736
#define OFF_WT2  (OFF_WT1 + 8388608ull)                           // 17337344
#define OFF_XBF  (OFF_WT2 + 8388608ull)                           // 25725952
#define OFF_H1   (OFF_XBF + 268435456ull)                         // 294161408
// END = OFF_H1 + SLOT_CAP*2048 = 563,645,440 bytes

typedef __bf16 bf16x8 __attribute__((ext_vector_type(8)));
typedef float f32x4 __attribute__((ext_vector_type(4)));
typedef unsigned short u16x4 __attribute__((ext_vector_type(4)));

__device__ __forceinline__ unsigned short f2bf(float f) {
  unsigned int u = __float_as_uint(f);
  u += 0x7fffu + ((u >> 16) & 1u);       // RNE
  return (unsigned short)(u >> 16);
}

__device__ __forceinline__ void gld_lds16(const void* g, void* l) {
  __builtin_amdgcn_global_load_lds(
      (const __attribute__((address_space(1))) void*)g,
      (__attribute__((address_space(3))) void*)l, 16, 0, 0);
}

// meta layout (ints): [0..3]=counts [4..7]=cursors [8..11]=seg [12..15]=padded counts

__global__ void k_hist(const int* __restrict__ levels, int n, int* __restrict__ meta) {
  __shared__ int h[NLVL];
  if (threadIdx.x < NLVL) h[threadIdx.x] = 0;
  __syncthreads();
  for (int t = blockIdx.x * blockDim.x + threadIdx.x; t < n; t += gridDim.x * blockDim.x)
    atomicAdd(&h[levels[t]], 1);
  __syncthreads();
  if (threadIdx.x < NLVL) atomicAdd(&meta[threadIdx.x], h[threadIdx.x]);
}

__global__ void k_seg(int* meta) {
  if (threadIdx.x == 0 && blockIdx.x == 0) {
    int s = 0;
    for (int l = 0; l < NLVL; ++l) {
      int pc = (meta[l] + 127) & ~127;
      meta[8 + l] = s;
      meta[12 + l] = pc;
      s += pc;
    }
  }
}

__global__ void k_scatter(const int* __restrict__ levels, int n,
                          int* __restrict__ meta, int* __restrict__ idx) {
  __shared__ int h[NLVL], base[NLVL], cur[NLVL];
  int t = blockIdx.x * blockDim.x + threadIdx.x;
  if (threadIdx.x < NLVL) { h[threadIdx.x] = 0; cur[threadIdx.x] = 0; }
  __syncthreads();
  int lvl = 0;
  if (t < n) { lvl = levels[t]; atomicAdd(&h[lvl], 1); }
  __syncthreads();
  if (threadIdx.x < NLVL)
    base[threadIdx.x] = atomicAdd(&meta[4 + threadIdx.x], h[threadIdx.x]);
  __syncthreads();
  if (t < n) {
    int p = atomicAdd(&cur[lvl], 1);
    idx[meta[8 + lvl] + base[lvl] + p] = t;
  }
}

__global__ void k_cvt_x(const f32x4* __restrict__ x, u16x4* __restrict__ xb, int n4) {
  for (int t = blockIdx.x * blockDim.x + threadIdx.x; t < n4; t += gridDim.x * blockDim.x) {
    f32x4 v = x[t];
    u16x4 o;
    o[0] = f2bf(v[0]); o[1] = f2bf(v[1]); o[2] = f2bf(v[2]); o[3] = f2bf(v[3]);
    xb[t] = o;
  }
}

// transpose-convert W[lvl][k][n] (fp32) -> Wt[lvl][n][k] (bf16)
__global__ void k_twt(const float* __restrict__ W, unsigned short* __restrict__ Wt) {
  __shared__ float tile[32][33];
  int lvl = blockIdx.z;
  int k0 = blockIdx.x * 32, n0 = blockIdx.y * 32;
  int tx = threadIdx.x, ty = threadIdx.y;
  const float* Wp = W + (size_t)lvl * 1048576;
  unsigned short* Wtp = Wt + (size_t)lvl * 1048576;
#pragma unroll
  for (int i = 0; i < 4; ++i)
    tile[ty + i * 8][tx] = Wp[(size_t)(k0 + ty + i * 8) * 1024 + n0 + tx];
  __syncthreads();
#pragma unroll
  for (int i = 0; i < 4; ++i) {
    int nn = ty + i * 8;
    Wtp[(size_t)(n0 + nn) * 1024 + k0 + tx] = f2bf(tile[tx][nn]);
  }
}

// Grouped GEMM, 128x128 tile, BK=64, 4 waves (2x2 of 64x64), mfma 16x16x32 bf16.
// Swapped operands: A-op = Wt rows (n,k), B-op = X rows (m,k) -> D[n][m]:
//   lane holds m = lane&15, n = (lane>>4)*4 + reg  (4 consecutive h-columns).
// PASS==1: A gathered via idx from x_bf16; epilogue relu(+b1) -> h1 bf16.
// PASS==2: A dense from h1; epilogue relu(+b2) dot W3 -> partial[slot][16].
template <int PASS>
__global__ __launch_bounds__(256) void k_gemm(
    const unsigned short* __restrict__ Asrc,
    const unsigned short* __restrict__ Wt,
    const float* __restrict__ bias,
    const float* __restrict__ w3,
    const int* __restrict__ meta,
    const int* __restrict__ idx,
    unsigned short* __restrict__ hout,
    float* __restrict__ partial) {
  const int lvl = blockIdx.z;
  const int mb = blockIdx.y;
  if (mb * 128 >= meta[12 + lvl]) return;   // beyond this level's padded rows
  const int nb = blockIdx.x;
  const int slotbase = meta[8 + lvl] + mb * 128;

  const int tid = threadIdx.x;
  const int ln = tid & 63;
  const int w = tid >> 6;
  const int wm = w >> 1, wn = w & 1;

  __shared__ unsigned short Xl[128 * 64];
  __shared__ unsigned short Wl[128 * 64];

  // staging: wave w stages rows [w*32, w*32+32) of each tile; 4 instrs x 8 rows
  const int srow = ln >> 3, schk = ln & 7;
  const unsigned short* ag[4];
  const unsigned short* wg[4];
  unsigned short* xd[4];
  unsigned short* wd[4];
#pragma unroll
  for (int j = 0; j < 4; ++j) {
    int rloc = w * 32 + j * 8 + srow;
    int arow = (PASS == 1) ? idx[slotbase + rloc] : (slotbase + rloc);
    ag[j] = Asrc + (size_t)arow * 1024 + schk * 8;
    wg[j] = Wt + ((size_t)lvl * 1024 + nb * 128 + rloc) * 1024 + schk * 8;
    xd[j] = &Xl[(w * 32 + j * 8) * 64];
    wd[j] = &Wl[(w * 32 + j * 8) * 64];
  }

  const f32x4 vzero = {0.f, 0.f, 0.f, 0.f};
  f32x4 acc[4][4];
#pragma unroll
  for (int a = 0; a < 4; ++a)
#pragma unroll
    for (int b = 0; b < 4; ++b) acc[a][b] = vzero;

  for (int k0 = 0; k0 < KDIM; k0 += 64) {
    __syncthreads();
#pragma unroll
    for (int j = 0; j < 4; ++j) gld_lds16(ag[j] + k0, xd[j]);
#pragma unroll
    for (int j = 0; j < 4; ++j) gld_lds16(wg[j] + k0, wd[j]);
    __syncthreads();
#pragma unroll
    for (int kk = 0; kk < 64; kk += 32) {
      bf16x8 aop[4], bop[4];
#pragma unroll
      for (int nf = 0; nf < 4; ++nf)
        aop[nf] = *(const bf16x8*)&Wl[(wn * 64 + nf * 16 + (ln & 15)) * 64 + kk + (ln >> 4) * 8];
#pragma unroll
      for (int mf = 0; mf < 4; ++mf)
        bop[mf] = *(const bf16x8*)&Xl[(wm * 64 + mf * 16 + (ln & 15)) * 64 + kk + (ln >> 4) * 8];
#pragma unroll
      for (int nf = 0; nf < 4; ++nf)
#pragma unroll
        for (int mf = 0; mf < 4; ++mf)
          acc[nf][mf] = __builtin_amdgcn_mfma_f32_16x16x32_bf16(aop[nf], bop[mf], acc[nf][mf], 0, 0, 0);
    }
  }

  const float* bv = bias + lvl * 1024;
  const int m_lo = ln & 15, n_lo = (ln >> 4) * 4;

  if (PASS == 1) {
#pragma unroll
    for (int nf = 0; nf < 4; ++nf) {
#pragma unroll
      for (int mf = 0; mf < 4; ++mf) {
        int slot = slotbase + wm * 64 + mf * 16 + m_lo;
        int col = nb * 128 + wn * 64 + nf * 16 + n_lo;
        f32x4 bb = *(const f32x4*)&bv[col];
        f32x4 v = acc[nf][mf];
        u16x4 o;
#pragma unroll
        for (int r = 0; r < 4; ++r) {
          float f = v[r] + bb[r];
          f = fmaxf(f, 0.f);
          o[r] = f2bf(f);
        }
        *(u16x4*)&hout[(size_t)slot * 1024 + col] = o;
      }
    }
  } else {
    const float* w3v = w3 + lvl * 1024;
    float ps[4] = {0.f, 0.f, 0.f, 0.f};
#pragma unroll
    for (int mf = 0; mf < 4; ++mf) {
#pragma unroll
      for (int nf = 0; nf < 4; ++nf) {
        int col = nb * 128 + wn * 64 + nf * 16 + n_lo;
        f32x4 bb = *(const f32x4*)&bv[col];
        f32x4 ww = *(const f32x4*)&w3v[col];
        f32x4 v = acc[nf][mf];
#pragma unroll
        for (int r = 0; r < 4; ++r) {
          float f = fmaxf(v[r] + bb[r], 0.f);
          ps[mf] += f * ww[r];
        }
      }
    }
#pragma unroll
    for (int mf = 0; mf < 4; ++mf) {
      float p = ps[mf];
      p += __shfl_xor(p, 16);
      p += __shfl_xor(p, 32);
      if (ln < 16) {
        int slot = slotbase + wm * 64 + mf * 16 + ln;
        partial[(size_t)slot * 16 + nb * 2 + wn] = p;
      }
    }
  }
}

__global__ void k_final(const int* __restrict__ meta, const int* __restrict__ idx,
                        const float* __restrict__ partial, const float* __restrict__ b3,
                        float* __restrict__ out) {
  int t = blockIdx.x * blockDim.x + threadIdx.x;
  int total = meta[11] + meta[15];
  if (t >= total) return;
  int lvl;
  if (t < meta[9]) lvl = 0;
  else if (t < meta[10]) lvl = 1;
  else if (t < meta[11]) lvl = 2;
  else lvl = 3;
  int local = t - meta[8 + lvl];
  if (local >= meta[lvl]) return;  // padding slot
  int row = idx[t];
  const float* pp = partial + (size_t)t * 16;
  float s = 0.f;
#pragma unroll
  for (int j = 0; j < 16; ++j) s += pp[j];
  out[row] = s + b3[lvl];
}

extern "C" void kernel_launch(void* const* d_in, const int* in_sizes, int n_in,
                              void* d_out, int out_size, void* d_ws, size_t ws_size,
                              hipStream_t stream) {
  const float* x      = (const float*)d_in[0];
  const int*   levels = (const int*)d_in[1];
  const float* W1     = (const float*)d_in[2];
  const float* b1     = (const float*)d_in[3];
  const float* W2     = (const float*)d_in[4];
  const float* b2     = (const float*)d_in[5];
  const float* W3     = (const float*)d_in[6];
  const float* b3     = (const float*)d_in[7];
  float* out = (float*)d_out;

  char* ws = (char*)d_ws;
  int* meta = (int*)ws;
  int* idx = (int*)(ws + OFF_IDX);
  float* partial = (float*)(ws + OFF_PART);
  unsigned short* Wt1 = (unsigned short*)(ws + OFF_WT1);
  unsigned short* Wt2 = (unsigned short*)(ws + OFF_WT2);
  unsigned short* xb  = (unsigned short*)(ws + OFF_XBF);
  unsigned short* h1  = (unsigned short*)(ws + OFF_H1);

  // zero meta + idx (padding slots -> row 0, safe finite data)
  hipMemsetAsync(d_ws, 0, OFF_IDX + (size_t)SLOT_CAP * 4, stream);
  k_hist<<<256, 256, 0, stream>>>(levels, NROWS, meta);
  k_seg<<<1, 64, 0, stream>>>(meta);
  k_scatter<<<512, 256, 0, stream>>>(levels, NROWS, meta, idx);
  k_cvt_x<<<2048, 256, 0, stream>>>((const f32x4*)x, (u16x4*)xb, NROWS * (KDIM / 4));
  k_twt<<<dim3(32, 32, 4), dim3(32, 8), 0, stream>>>(W1, Wt1);
  k_twt<<<dim3(32, 32, 4), dim3(32, 8), 0, stream>>>(W2, Wt2);

  dim3 gg(8, 1024, 4);
  k_gemm<1><<<gg, 256, 0, stream>>>(xb, Wt1, b1, nullptr, meta, idx, h1, nullptr);
  k_gemm<2><<<gg, 256, 0, stream>>>(h1, Wt2, b2, W3, meta, idx, nullptr, partial);

  k_final<<<514, 256, 0, stream>>>(meta, idx, partial, b3, out);
}

// Round 2
// 960.073 us; speedup vs baseline: 1.1502x; 1.1502x over previous
//
#include <hip/hip_runtime.h>

// ---------------- problem constants ----------------
#define NROWS   131072
#define KDIM    1024
#define NLVL    4
#define SLOT_CAP 131584            // 131072 + 4*128 padding
#define NSB     1028               // SLOT_CAP / 128 slot-blocks

// ---------------- ws layout (bytes) ----------------
#define OFF_IDX  1024ull
#define OFF_PART (OFF_IDX + (size_t)SLOT_CAP * 4)                 // 527360
#define OFF_WT1  (OFF_PART + (size_t)SLOT_CAP * 64)               // 8948736
#define OFF_WT2  (OFF_WT1 + 8388608ull)                           // 17337344
#define OFF_XBF  (OFF_WT2 + 8388608ull)                           // 25725952
#define OFF_H1   (OFF_XBF + 268435456ull)                         // 294161408
// END = OFF_H1 + SLOT_CAP*2048 = 563,645,440 bytes

typedef __bf16 bf16x8 __attribute__((ext_vector_type(8)));
typedef float f32x4 __attribute__((ext_vector_type(4)));
typedef unsigned short u16x4 __attribute__((ext_vector_type(4)));

__device__ __forceinline__ unsigned short f2bf(float f) {
  unsigned int u = __float_as_uint(f);
  u += 0x7fffu + ((u >> 16) & 1u);       // RNE
  return (unsigned short)(u >> 16);
}

__device__ __forceinline__ void gld_lds16(const void* g, void* l) {
  __builtin_amdgcn_global_load_lds(
      (const __attribute__((address_space(1))) void*)g,
      (__attribute__((address_space(3))) void*)l, 16, 0, 0);
}

// meta layout (ints): [0..3]=counts [4..7]=cursors [8..11]=seg [12..15]=padded counts

__global__ void k_hist(const int* __restrict__ levels, int n, int* __restrict__ meta) {
  __shared__ int h[NLVL];
  if (threadIdx.x < NLVL) h[threadIdx.x] = 0;
  __syncthreads();
  for (int t = blockIdx.x * blockDim.x + threadIdx.x; t < n; t += gridDim.x * blockDim.x)
    atomicAdd(&h[levels[t]], 1);
  __syncthreads();
  if (threadIdx.x < NLVL) atomicAdd(&meta[threadIdx.x], h[threadIdx.x]);
}

__global__ void k_seg(int* meta) {
  if (threadIdx.x == 0 && blockIdx.x == 0) {
    int s = 0;
    for (int l = 0; l < NLVL; ++l) {
      int pc = (meta[l] + 127) & ~127;
      meta[8 + l] = s;
      meta[12 + l] = pc;
      s += pc;
    }
  }
}

__global__ void k_scatter(const int* __restrict__ levels, int n,
                          int* __restrict__ meta, int* __restrict__ idx) {
  __shared__ int h[NLVL], base[NLVL], cur[NLVL];
  int t = blockIdx.x * blockDim.x + threadIdx.x;
  if (threadIdx.x < NLVL) { h[threadIdx.x] = 0; cur[threadIdx.x] = 0; }
  __syncthreads();
  int lvl = 0;
  if (t < n) { lvl = levels[t]; atomicAdd(&h[lvl], 1); }
  __syncthreads();
  if (threadIdx.x < NLVL)
    base[threadIdx.x] = atomicAdd(&meta[4 + threadIdx.x], h[threadIdx.x]);
  __syncthreads();
  if (t < n) {
    int p = atomicAdd(&cur[lvl], 1);
    idx[meta[8 + lvl] + base[lvl] + p] = t;
  }
}

__global__ void k_cvt_x(const f32x4* __restrict__ x, u16x4* __restrict__ xb, int n4) {
  for (int t = blockIdx.x * blockDim.x + threadIdx.x; t < n4; t += gridDim.x * blockDim.x) {
    f32x4 v = x[t];
    u16x4 o;
    o[0] = f2bf(v[0]); o[1] = f2bf(v[1]); o[2] = f2bf(v[2]); o[3] = f2bf(v[3]);
    xb[t] = o;
  }
}

// transpose-convert W[lvl][k][n] (fp32) -> Wt[lvl][n][k] (bf16)
__global__ void k_twt(const float* __restrict__ W, unsigned short* __restrict__ Wt) {
  __shared__ float tile[32][33];
  int lvl = blockIdx.z;
  int k0 = blockIdx.x * 32, n0 = blockIdx.y * 32;
  int tx = threadIdx.x, ty = threadIdx.y;
  const float* Wp = W + (size_t)lvl * 1048576;
  unsigned short* Wtp = Wt + (size_t)lvl * 1048576;
#pragma unroll
  for (int i = 0; i < 4; ++i)
    tile[ty + i * 8][tx] = Wp[(size_t)(k0 + ty + i * 8) * 1024 + n0 + tx];
  __syncthreads();
#pragma unroll
  for (int i = 0; i < 4; ++i) {
    int nn = ty + i * 8;
    Wtp[(size_t)(n0 + nn) * 1024 + k0 + tx] = f2bf(tile[tx][nn]);
  }
}

// Grouped GEMM, 128x128 tile, BK=64, 4 waves (2x2 of 64x64), mfma 16x16x32 bf16.
// Swapped operands: A-op = Wt rows (n,k), B-op = X rows (m,k) -> D[n][m]:
//   lane holds m = lane&15, n = (lane>>4)*4 + reg  (4 consecutive h-columns).
// 1-D grid over (slot-block sb [0..NSB), col-block nb [0..8)) with XCD-chunked
// swizzle: all 8 nb of one sb land on the SAME XCD (X-tile fetched once/XCD),
// consecutive sb share the L2-resident W level.
// LDS bank-conflict fix (rule #21): dest stays linear; global SOURCE chunk is
// pre-permuted by chunk^=(row&7), read side applies the same XOR.
// PASS==1: A gathered via idx from x_bf16; epilogue relu(+b1) -> h1 bf16.
// PASS==2: A dense from h1; epilogue relu(+b2) dot W3 -> partial[slot][16].
template <int PASS>
__global__ __launch_bounds__(256) void k_gemm(
    const unsigned short* __restrict__ Asrc,
    const unsigned short* __restrict__ Wt,
    const float* __restrict__ bias,
    const float* __restrict__ w3,
    const int* __restrict__ meta,
    const int* __restrict__ idx,
    unsigned short* __restrict__ hout,
    float* __restrict__ partial) {
  // XCD-chunked bijective swizzle over 8*NSB blocks: bid%8 = XCD (empirical
  // round-robin); each XCD walks NSB consecutive swz values, nb innermost.
  const int bid = blockIdx.x;
  const int swz = (bid & 7) * NSB + (bid >> 3);
  const int nb = swz & 7;
  const int sb = swz >> 3;

  const int slotbase = sb * 128;
  if (slotbase >= meta[11] + meta[15]) return;   // beyond total padded rows
  int lvl;
  if      (slotbase < meta[9])  lvl = 0;
  else if (slotbase < meta[10]) lvl = 1;
  else if (slotbase < meta[11]) lvl = 2;
  else                          lvl = 3;

  const int tid = threadIdx.x;
  const int ln = tid & 63;
  const int w = tid >> 6;
  const int wm = w >> 1, wn = w & 1;

  __shared__ unsigned short Xl[128 * 64];
  __shared__ unsigned short Wl[128 * 64];

  // staging: wave w stages rows [w*32, w*32+32); lane l -> row l>>3, phys
  // chunk l&7 of its 8-row group. Source chunk = (l&7)^(l>>3) implements the
  // read-side XOR swizzle with a linear LDS destination.
  const int srow = ln >> 3;
  const int schk = (ln & 7) ^ srow;
  const unsigned short* ag[4];
  const unsigned short* wg[4];
  unsigned short* xd[4];
  unsigned short* wd[4];
#pragma unroll
  for (int j = 0; j < 4; ++j) {
    int rloc = w * 32 + j * 8 + srow;
    int arow = (PASS == 1) ? idx[slotbase + rloc] : (slotbase + rloc);
    ag[j] = Asrc + (size_t)arow * 1024 + schk * 8;
    wg[j] = Wt + ((size_t)lvl * 1024 + nb * 128 + rloc) * 1024 + schk * 8;
    xd[j] = &Xl[(w * 32 + j * 8) * 64];
    wd[j] = &Wl[(w * 32 + j * 8) * 64];
  }

  const f32x4 vzero = {0.f, 0.f, 0.f, 0.f};
  f32x4 acc[4][4];
#pragma unroll
  for (int a = 0; a < 4; ++a)
#pragma unroll
    for (int b = 0; b < 4; ++b) acc[a][b] = vzero;

  const int rx = ln & 7;           // row&7 of every fragment row this lane reads
  const int kg = ln >> 4;          // k-group 0..3

  for (int k0 = 0; k0 < KDIM; k0 += 64) {
    __syncthreads();
#pragma unroll
    for (int j = 0; j < 4; ++j) gld_lds16(ag[j] + k0, xd[j]);
#pragma unroll
    for (int j = 0; j < 4; ++j) gld_lds16(wg[j] + k0, wd[j]);
    __syncthreads();
#pragma unroll
    for (int kk = 0; kk < 64; kk += 32) {
      const int chk = (((kk >> 3) + kg) ^ rx) * 8;   // swizzled 8-elem chunk
      bf16x8 aop[4], bop[4];
#pragma unroll
      for (int nf = 0; nf < 4; ++nf)
        aop[nf] = *(const bf16x8*)&Wl[(wn * 64 + nf * 16 + (ln & 15)) * 64 + chk];
#pragma unroll
      for (int mf = 0; mf < 4; ++mf)
        bop[mf] = *(const bf16x8*)&Xl[(wm * 64 + mf * 16 + (ln & 15)) * 64 + chk];
#pragma unroll
      for (int nf = 0; nf < 4; ++nf)
#pragma unroll
        for (int mf = 0; mf < 4; ++mf)
          acc[nf][mf] = __builtin_amdgcn_mfma_f32_16x16x32_bf16(aop[nf], bop[mf], acc[nf][mf], 0, 0, 0);
    }
  }

  const float* bv = bias + lvl * 1024;
  const int m_lo = ln & 15, n_lo = (ln >> 4) * 4;

  if (PASS == 1) {
#pragma unroll
    for (int nf = 0; nf < 4; ++nf) {
#pragma unroll
      for (int mf = 0; mf < 4; ++mf) {
        int slot = slotbase + wm * 64 + mf * 16 + m_lo;
        int col = nb * 128 + wn * 64 + nf * 16 + n_lo;
        f32x4 bb = *(const f32x4*)&bv[col];
        f32x4 v = acc[nf][mf];
        u16x4 o;
#pragma unroll
        for (int r = 0; r < 4; ++r) {
          float f = v[r] + bb[r];
          f = fmaxf(f, 0.f);
          o[r] = f2bf(f);
        }
        *(u16x4*)&hout[(size_t)slot * 1024 + col] = o;
      }
    }
  } else {
    const float* w3v = w3 + lvl * 1024;
    float ps[4] = {0.f, 0.f, 0.f, 0.f};
#pragma unroll
    for (int mf = 0; mf < 4; ++mf) {
#pragma unroll
      for (int nf = 0; nf < 4; ++nf) {
        int col = nb * 128 + wn * 64 + nf * 16 + n_lo;
        f32x4 bb = *(const f32x4*)&bv[col];
        f32x4 ww = *(const f32x4*)&w3v[col];
        f32x4 v = acc[nf][mf];
#pragma unroll
        for (int r = 0; r < 4; ++r) {
          float f = fmaxf(v[r] + bb[r], 0.f);
          ps[mf] += f * ww[r];
        }
      }
    }
#pragma unroll
    for (int mf = 0; mf < 4; ++mf) {
      float p = ps[mf];
      p += __shfl_xor(p, 16);
      p += __shfl_xor(p, 32);
      if (ln < 16) {
        int slot = slotbase + wm * 64 + mf * 16 + ln;
        partial[(size_t)slot * 16 + nb * 2 + wn] = p;
      }
    }
  }
}

__global__ void k_final(const int* __restrict__ meta, const int* __restrict__ idx,
                        const float* __restrict__ partial, const float* __restrict__ b3,
                        float* __restrict__ out) {
  int t = blockIdx.x * blockDim.x + threadIdx.x;
  int total = meta[11] + meta[15];
  if (t >= total) return;
  int lvl;
  if (t < meta[9]) lvl = 0;
  else if (t < meta[10]) lvl = 1;
  else if (t < meta[11]) lvl = 2;
  else lvl = 3;
  int local = t - meta[8 + lvl];
  if (local >= meta[lvl]) return;  // padding slot
  int row = idx[t];
  const float* pp = partial + (size_t)t * 16;
  float s = 0.f;
#pragma unroll
  for (int j = 0; j < 16; ++j) s += pp[j];
  out[row] = s + b3[lvl];
}

extern "C" void kernel_launch(void* const* d_in, const int* in_sizes, int n_in,
                              void* d_out, int out_size, void* d_ws, size_t ws_size,
                              hipStream_t stream) {
  const float* x      = (const float*)d_in[0];
  const int*   levels = (const int*)d_in[1];
  const float* W1     = (const float*)d_in[2];
  const float* b1     = (const float*)d_in[3];
  const float* W2     = (const float*)d_in[4];
  const float* b2     = (const float*)d_in[5];
  const float* W3     = (const float*)d_in[6];
  const float* b3     = (const float*)d_in[7];
  float* out = (float*)d_out;

  char* ws = (char*)d_ws;
  int* meta = (int*)ws;
  int* idx = (int*)(ws + OFF_IDX);
  float* partial = (float*)(ws + OFF_PART);
  unsigned short* Wt1 = (unsigned short*)(ws + OFF_WT1);
  unsigned short* Wt2 = (unsigned short*)(ws + OFF_WT2);
  unsigned short* xb  = (unsigned short*)(ws + OFF_XBF);
  unsigned short* h1  = (unsigned short*)(ws + OFF_H1);

  // zero meta + idx (padding slots -> row 0, safe finite data)
  hipMemsetAsync(d_ws, 0, OFF_IDX + (size_t)SLOT_CAP * 4, stream);
  k_hist<<<256, 256, 0, stream>>>(levels, NROWS, meta);
  k_seg<<<1, 64, 0, stream>>>(meta);
  k_scatter<<<512, 256, 0, stream>>>(levels, NROWS, meta, idx);
  k_cvt_x<<<2048, 256, 0, stream>>>((const f32x4*)x, (u16x4*)xb, NROWS * (KDIM / 4));
  k_twt<<<dim3(32, 32, 4), dim3(32, 8), 0, stream>>>(W1, Wt1);
  k_twt<<<dim3(32, 32, 4), dim3(32, 8), 0, stream>>>(W2, Wt2);

  k_gemm<1><<<8 * NSB, 256, 0, stream>>>(xb, Wt1, b1, nullptr, meta, idx, h1, nullptr);
  k_gemm<2><<<8 * NSB, 256, 0, stream>>>(h1, Wt2, b2, W3, meta, idx, nullptr, partial);

  k_final<<<514, 256, 0, stream>>>(meta, idx, partial, b3, out);
}

// Round 3
// 811.845 us; speedup vs baseline: 1.3602x; 1.1826x over previous
//
#include <hip/hip_runtime.h>

// ---------------- problem constants ----------------
#define NROWS   131072
#define KDIM    1024
#define NLVL    4
#define SLOT_CAP 132096            // 131072 + 4*256 padding
#define NSB     516                // SLOT_CAP / 256 slot-blocks

// ---------------- ws layout (bytes) ----------------
#define OFF_IDX  1024ull
#define OFF_PART (OFF_IDX + (size_t)SLOT_CAP * 4)
#define OFF_WT1  (OFF_PART + (size_t)SLOT_CAP * 64)
#define OFF_WT2  (OFF_WT1 + 8388608ull)
#define OFF_XBF  (OFF_WT2 + 8388608ull)
#define OFF_H1   (OFF_XBF + 268435456ull)
// END = OFF_H1 + SLOT_CAP*2048 = 564,728,832 bytes

typedef __bf16 bf16x8 __attribute__((ext_vector_type(8)));
typedef float f32x4 __attribute__((ext_vector_type(4)));
typedef unsigned short u16x4 __attribute__((ext_vector_type(4)));

__device__ __forceinline__ unsigned short f2bf(float f) {
  unsigned int u = __float_as_uint(f);
  u += 0x7fffu + ((u >> 16) & 1u);       // RNE
  return (unsigned short)(u >> 16);
}

__device__ __forceinline__ void gld_lds16(const void* g, void* l) {
  __builtin_amdgcn_global_load_lds(
      (const __attribute__((address_space(1))) void*)g,
      (__attribute__((address_space(3))) void*)l, 16, 0, 0);
}

// meta layout (ints): [0..3]=counts [4..7]=cursors [8..11]=seg [12..15]=padded counts

__global__ void k_hist(const int* __restrict__ levels, int n, int* __restrict__ meta) {
  __shared__ int h[NLVL];
  if (threadIdx.x < NLVL) h[threadIdx.x] = 0;
  __syncthreads();
  for (int t = blockIdx.x * blockDim.x + threadIdx.x; t < n; t += gridDim.x * blockDim.x)
    atomicAdd(&h[levels[t]], 1);
  __syncthreads();
  if (threadIdx.x < NLVL) atomicAdd(&meta[threadIdx.x], h[threadIdx.x]);
}

__global__ void k_seg(int* meta) {
  if (threadIdx.x == 0 && blockIdx.x == 0) {
    int s = 0;
    for (int l = 0; l < NLVL; ++l) {
      int pc = (meta[l] + 255) & ~255;
      meta[8 + l] = s;
      meta[12 + l] = pc;
      s += pc;
    }
  }
}

__global__ void k_scatter(const int* __restrict__ levels, int n,
                          int* __restrict__ meta, int* __restrict__ idx) {
  __shared__ int h[NLVL], base[NLVL], cur[NLVL];
  int t = blockIdx.x * blockDim.x + threadIdx.x;
  if (threadIdx.x < NLVL) { h[threadIdx.x] = 0; cur[threadIdx.x] = 0; }
  __syncthreads();
  int lvl = 0;
  if (t < n) { lvl = levels[t]; atomicAdd(&h[lvl], 1); }
  __syncthreads();
  if (threadIdx.x < NLVL)
    base[threadIdx.x] = atomicAdd(&meta[4 + threadIdx.x], h[threadIdx.x]);
  __syncthreads();
  if (t < n) {
    int p = atomicAdd(&cur[lvl], 1);
    idx[meta[8 + lvl] + base[lvl] + p] = t;
  }
}

__global__ void k_cvt_x(const f32x4* __restrict__ x, u16x4* __restrict__ xb, int n4) {
  for (int t = blockIdx.x * blockDim.x + threadIdx.x; t < n4; t += gridDim.x * blockDim.x) {
    f32x4 v = x[t];
    u16x4 o;
    o[0] = f2bf(v[0]); o[1] = f2bf(v[1]); o[2] = f2bf(v[2]); o[3] = f2bf(v[3]);
    xb[t] = o;
  }
}

// transpose-convert W[lvl][k][n] (fp32) -> Wt[lvl][n][k] (bf16)
__global__ void k_twt(const float* __restrict__ W, unsigned short* __restrict__ Wt) {
  __shared__ float tile[32][33];
  int lvl = blockIdx.z;
  int k0 = blockIdx.x * 32, n0 = blockIdx.y * 32;
  int tx = threadIdx.x, ty = threadIdx.y;
  const float* Wp = W + (size_t)lvl * 1048576;
  unsigned short* Wtp = Wt + (size_t)lvl * 1048576;
#pragma unroll
  for (int i = 0; i < 4; ++i)
    tile[ty + i * 8][tx] = Wp[(size_t)(k0 + ty + i * 8) * 1024 + n0 + tx];
  __syncthreads();
#pragma unroll
  for (int i = 0; i < 4; ++i) {
    int nn = ty + i * 8;
    Wtp[(size_t)(n0 + nn) * 1024 + k0 + tx] = f2bf(tile[tx][nn]);
  }
}

// ---------------------------------------------------------------------------
// 256x256 8-phase grouped GEMM (T2+T3+T4+T5), BK=64, 8 waves (2m x 4n),
// mfma 16x16x32 bf16, per-wave output 128(m) x 64(n), acc[4][8] f32x4.
//
// LDS: 8 half-tile slots of 16KB = 128KB. Slot(s) = ((tile&1)*4 + isX*2 + kk).
// Each slot: 256 rows x 32 k-cols bf16, 64B rows, chunk-XOR swizzle
// ((row>>1)&3) applied on BOTH sides (pre-swizzled global source for the
// linear global_load_lds dest; same XOR on ds_read) -> b128 reads at the
// 8-lanes/bank minimum.
//
// Phases per 2 K-tiles (t0 even from parity-0 slots, t1 odd):
//  P1 rd W(k0)+X(k0,m0-3) | stage t1.Xk1        | MMA mh0
//  P2 rd X(k0,m4-7)       | stage (t0+2).Wk0    | MMA mh1
//  P3 rd W(k1)+X(k1,m0-3) | stage (t0+2).Xk0    | MMA mh0
//  P4 rd X(k1,m4-7)       | stage (t0+2).Wk1    | MMA mh1   [vmcnt(6)]
//  P5..P8 same on parity 1 (stages (t0+2).Xk1, (t1+2).Wk0/Xk0/Wk1) [vmcnt(6)@P8]
// Each stage lands in the slot freed exactly one phase earlier; counted
// vmcnt(6) = 3 half-tiles in flight; stage->consume gap ~7 phases.
// ---------------------------------------------------------------------------
#define BARR __builtin_amdgcn_s_barrier()
#define WAIT_L  asm volatile("s_waitcnt lgkmcnt(0)" ::: "memory")
#define WAIT_V6 asm volatile("s_waitcnt vmcnt(6) lgkmcnt(0)" ::: "memory")
#define PRIO(x) __builtin_amdgcn_s_setprio(x)

#define RD_W(pi,kk) { const char* p_ = lds + (((pi)*4 + (kk)) << 14) + offW0; \
  wf[0] = *(const bf16x8*)(p_);        wf[1] = *(const bf16x8*)(p_ + 1024);  \
  wf[2] = *(const bf16x8*)(p_ + 2048); wf[3] = *(const bf16x8*)(p_ + 3072); }
#define RD_X(pi,kk,mh) { const char* p_ = lds + (((pi)*4 + 2 + (kk)) << 14) + offX0 + (mh)*4096; \
  xf[0] = *(const bf16x8*)(p_);        xf[1] = *(const bf16x8*)(p_ + 1024);  \
  xf[2] = *(const bf16x8*)(p_ + 2048); xf[3] = *(const bf16x8*)(p_ + 3072); }
#define MMA(mh) { _Pragma("unroll") for (int nf_ = 0; nf_ < 4; ++nf_) { \
  _Pragma("unroll") for (int j_ = 0; j_ < 4; ++j_) \
    acc[nf_][(mh)*4 + j_] = __builtin_amdgcn_mfma_f32_16x16x32_bf16(wf[nf_], xf[j_], acc[nf_][(mh)*4 + j_], 0, 0, 0); } }

template <int PASS>
__global__ __launch_bounds__(512, 2) void k_gemm(
    const unsigned short* __restrict__ Asrc,
    const unsigned short* __restrict__ Wt,
    const float* __restrict__ bias,
    const float* __restrict__ w3,
    const int* __restrict__ meta,
    const int* __restrict__ idx,
    unsigned short* __restrict__ hout,
    float* __restrict__ partial) {
  __shared__ __align__(16) char lds[131072];

  // XCD-chunked bijective swizzle over NSB*4 = 2064 blocks (2064 % 8 == 0):
  // all 4 nb of one sb consecutive on the same XCD; consecutive sb share lvl's W.
  const int bid = blockIdx.x;
  const int swz = (bid & 7) * (NSB * 4 / 8) + (bid >> 3);
  const int nb = swz & 3;
  const int sb = swz >> 2;
  const int slotbase = sb * 256;
  if (slotbase >= meta[11] + meta[15]) return;
  int lvl;
  if      (slotbase < meta[9])  lvl = 0;
  else if (slotbase < meta[10]) lvl = 1;
  else if (slotbase < meta[11]) lvl = 2;
  else                          lvl = 3;

  const int tid = threadIdx.x;
  const int ln  = tid & 63;
  const int w   = tid >> 6;          // wave 0..7
  const int wn  = w & 3;             // n-quadrant (4 waves)
  const int wm  = w >> 2;            // m-half (2 waves)
  const int l15 = ln & 15;

  // ---- staging lane constants (wave stages rows w*16..w*16+15 per round) ----
  const int rr0 = w * 16 + (ln >> 2);            // round-0 row 0..127
  const int cch = (ln & 3) ^ ((rr0 >> 1) & 3);   // pre-swizzled source chunk
  int ar0, ar1;
  if (PASS == 1) { ar0 = idx[slotbase + rr0]; ar1 = idx[slotbase + rr0 + 128]; }
  else           { ar0 = slotbase + rr0;      ar1 = slotbase + rr0 + 128; }
  const char* xs0 = (const char*)Asrc + (size_t)ar0 * 2048 + cch * 16;
  const char* xs1 = (const char*)Asrc + (size_t)ar1 * 2048 + cch * 16;
  const char* wlv = (const char*)Wt + ((size_t)lvl << 21);
  const char* ws0 = wlv + (size_t)(nb * 256 + rr0) * 2048 + cch * 16;
  const char* ws1 = ws0 + 128 * 2048;

  auto STG = [&](int t, int isX, int kkh) {
    char* db = (char*)lds + (((t & 1) * 4 + isX * 2 + kkh) << 14) + (w << 10);
    const char* s0 = isX ? xs0 : ws0;
    const char* s1 = isX ? xs1 : ws1;
    const int o = t * 128 + kkh * 64;
    gld_lds16(s0 + o, db);
    gld_lds16(s1 + o, db + 8192);
  };

  // ---- fragment read offsets (same XOR as staging; +16 rows = +1024B) ----
  const int xorc  = ((ln >> 4) ^ ((l15 >> 1) & 3)) * 16;
  const int offW0 = (wn * 64 + l15) * 64 + xorc;
  const int offX0 = (wm * 128 + l15) * 64 + xorc;

  const f32x4 vzero = {0.f, 0.f, 0.f, 0.f};
  f32x4 acc[4][8];
#pragma unroll
  for (int a = 0; a < 4; ++a)
#pragma unroll
    for (int b = 0; b < 8; ++b) acc[a][b] = vzero;
  bf16x8 wf[4], xf[4];

  // ---- prologue: tile0 complete + tile1 {Wk0,Xk0,Wk1} = 7 half-tiles ----
  STG(0, 0, 0); STG(0, 1, 0); STG(0, 0, 1); STG(0, 1, 1);
  STG(1, 0, 0); STG(1, 1, 0); STG(1, 0, 1);
  asm volatile("s_waitcnt vmcnt(6)" ::: "memory");   // tile0's 8 loads landed
  BARR;

  for (int i = 0; i < 8; ++i) {                      // 16 K-tiles, 2 per iter
    const int t0 = 2 * i, t1 = 2 * i + 1;
    const bool g = (i < 7);
    // P1
    RD_W(0, 0); RD_X(0, 0, 0); STG(t1, 1, 1);
    BARR; WAIT_L; PRIO(1); MMA(0); PRIO(0); BARR;
    // P2
    RD_X(0, 0, 1); if (g) STG(t0 + 2, 0, 0);
    BARR; WAIT_L; PRIO(1); MMA(1); PRIO(0); BARR;
    // P3
    RD_W(0, 1); RD_X(0, 1, 0); if (g) STG(t0 + 2, 1, 0);
    BARR; WAIT_L; PRIO(1); MMA(0); PRIO(0); BARR;
    // P4
    RD_X(0, 1, 1); if (g) STG(t0 + 2, 0, 1);
    BARR; WAIT_V6; PRIO(1); MMA(1); PRIO(0); BARR;
    // P5
    RD_W(1, 0); RD_X(1, 0, 0); if (g) STG(t0 + 2, 1, 1);
    BARR; WAIT_L; PRIO(1); MMA(0); PRIO(0); BARR;
    // P6
    RD_X(1, 0, 1); if (g) STG(t1 + 2, 0, 0);
    BARR; WAIT_L; PRIO(1); MMA(1); PRIO(0); BARR;
    // P7
    RD_W(1, 1); RD_X(1, 1, 0); if (g) STG(t1 + 2, 1, 0);
    BARR; WAIT_L; PRIO(1); MMA(0); PRIO(0); BARR;
    // P8
    RD_X(1, 1, 1); if (g) STG(t1 + 2, 0, 1);
    BARR; WAIT_V6; PRIO(1); MMA(1); PRIO(0); BARR;
  }

  // ---- epilogue ----
  const float* bv = bias + lvl * 1024;
  const int n_lo = (ln >> 4) * 4;

  if (PASS == 1) {
#pragma unroll
    for (int nf = 0; nf < 4; ++nf) {
#pragma unroll
      for (int mf = 0; mf < 8; ++mf) {
        int slot = slotbase + wm * 128 + mf * 16 + l15;
        int col = nb * 256 + wn * 64 + nf * 16 + n_lo;
        f32x4 bb = *(const f32x4*)&bv[col];
        f32x4 v = acc[nf][mf];
        u16x4 o;
#pragma unroll
        for (int r = 0; r < 4; ++r) o[r] = f2bf(fmaxf(v[r] + bb[r], 0.f));
        *(u16x4*)&hout[(size_t)slot * 1024 + col] = o;
      }
    }
  } else {
    const float* w3v = w3 + lvl * 1024;
    float ps[8] = {0.f, 0.f, 0.f, 0.f, 0.f, 0.f, 0.f, 0.f};
#pragma unroll
    for (int mf = 0; mf < 8; ++mf) {
#pragma unroll
      for (int nf = 0; nf < 4; ++nf) {
        int col = nb * 256 + wn * 64 + nf * 16 + n_lo;
        f32x4 bb = *(const f32x4*)&bv[col];
        f32x4 ww = *(const f32x4*)&w3v[col];
        f32x4 v = acc[nf][mf];
#pragma unroll
        for (int r = 0; r < 4; ++r) ps[mf] += fmaxf(v[r] + bb[r], 0.f) * ww[r];
      }
    }
#pragma unroll
    for (int mf = 0; mf < 8; ++mf) {
      float p = ps[mf];
      p += __shfl_xor(p, 16);
      p += __shfl_xor(p, 32);
      if (ln < 16) {
        int slot = slotbase + wm * 128 + mf * 16 + ln;
        partial[(size_t)slot * 16 + nb * 4 + wn] = p;
      }
    }
  }
}

__global__ void k_final(const int* __restrict__ meta, const int* __restrict__ idx,
                        const float* __restrict__ partial, const float* __restrict__ b3,
                        float* __restrict__ out) {
  int t = blockIdx.x * blockDim.x + threadIdx.x;
  int total = meta[11] + meta[15];
  if (t >= total) return;
  int lvl;
  if (t < meta[9]) lvl = 0;
  else if (t < meta[10]) lvl = 1;
  else if (t < meta[11]) lvl = 2;
  else lvl = 3;
  int local = t - meta[8 + lvl];
  if (local >= meta[lvl]) return;  // padding slot
  int row = idx[t];
  const float* pp = partial + (size_t)t * 16;
  float s = 0.f;
#pragma unroll
  for (int j = 0; j < 16; ++j) s += pp[j];
  out[row] = s + b3[lvl];
}

extern "C" void kernel_launch(void* const* d_in, const int* in_sizes, int n_in,
                              void* d_out, int out_size, void* d_ws, size_t ws_size,
                              hipStream_t stream) {
  const float* x      = (const float*)d_in[0];
  const int*   levels = (const int*)d_in[1];
  const float* W1     = (const float*)d_in[2];
  const float* b1     = (const float*)d_in[3];
  const float* W2     = (const float*)d_in[4];
  const float* b2     = (const float*)d_in[5];
  const float* W3     = (const float*)d_in[6];
  const float* b3     = (const float*)d_in[7];
  float* out = (float*)d_out;

  char* ws = (char*)d_ws;
  int* meta = (int*)ws;
  int* idx = (int*)(ws + OFF_IDX);
  float* partial = (float*)(ws + OFF_PART);
  unsigned short* Wt1 = (unsigned short*)(ws + OFF_WT1);
  unsigned short* Wt2 = (unsigned short*)(ws + OFF_WT2);
  unsigned short* xb  = (unsigned short*)(ws + OFF_XBF);
  unsigned short* h1  = (unsigned short*)(ws + OFF_H1);

  // zero meta + idx (padding slots -> row 0, safe finite data)
  hipMemsetAsync(d_ws, 0, OFF_IDX + (size_t)SLOT_CAP * 4, stream);
  k_hist<<<256, 256, 0, stream>>>(levels, NROWS, meta);
  k_seg<<<1, 64, 0, stream>>>(meta);
  k_scatter<<<512, 256, 0, stream>>>(levels, NROWS, meta, idx);
  k_cvt_x<<<2048, 256, 0, stream>>>((const f32x4*)x, (u16x4*)xb, NROWS * (KDIM / 4));
  k_twt<<<dim3(32, 32, 4), dim3(32, 8), 0, stream>>>(W1, Wt1);
  k_twt<<<dim3(32, 32, 4), dim3(32, 8), 0, stream>>>(W2, Wt2);

  k_gemm<1><<<NSB * 4, 512, 0, stream>>>(xb, Wt1, b1, nullptr, meta, idx, h1, nullptr);
  k_gemm<2><<<NSB * 4, 512, 0, stream>>>(h1, Wt2, b2, W3, meta, idx, nullptr, partial);

  k_final<<<516, 256, 0, stream>>>(meta, idx, partial, b3, out);
}